// Round 10
// baseline (247.830 us; speedup 1.0000x reference)
//
#include <hip/hip_runtime.h>
#include <hip/hip_bf16.h>

// NeighborAttention on MI355X. fp32 in/out, int32 mask.
// KEY INSIGHT (R0): query = broadcast of masked neighbor-mean -> all seq
// positions share one query per (b,h). Attention collapses to GEMV-scale work.
// Recorded findings: device-wide SW barriers ~40us each (R6/R7, dead end);
// graph-replay launch gaps ~1us (R8: -3 launches = -3us); timed loop carries
// ~41us fixed ws-poison fill + ~10us restore (harness-side, untouchable).
// R9: the ~115us kernel budget is dominated by k_scores/k_wpe at 512 blocks
// = 2 blocks/CU -> latency-exposed staging. This round: 1024 blocks each
// (s-chunk 64->32), k_scores lane covers (s, d-half) merged by shfl_xor(32),
// k_wpe keeps 8-deep float4 ILP. 32 num-slabs (+8.5MB traffic, 2x occupancy).

#define DIM  1024
#define NH   16
#define HD   64
#define BS   8
#define SEQ  1024
#define NNB  50

// workspace offsets (floats), all 16B-aligned
#define OF_P     16
#define OF_SCP   131088
#define OF_NUMP  655376       // 32 slabs x 131072
#define OF_DENP  4849680
#define OF_XW    4853776
#define OF_CTX   4984848
#define OF_OUTR  4993040      // total ~20 MB of ~256 MB ws

// ---------------- K1: fused neighbor-pool + q + p, one block per (h,b) -------
__global__ void k_prep(const float* __restrict__ xnb, const float* __restrict__ nm,
                       const float* __restrict__ qw, const float* __restrict__ qb,
                       const float* __restrict__ kw, float* __restrict__ p){
  int h = blockIdx.x & 15, b = blockIdx.x >> 4;
  int tid = threadIdx.x, wv = tid >> 6, ln = tid & 63;
  __shared__ float xnl[1024];
  __shared__ float qp[256];
  __shared__ float ql[64];
  {  // masked neighbor mean
    int d = tid*4;
    float4 acc = {0,0,0,0}; float wsum = 0.f;
    #pragma unroll 10
    for (int n=0; n<NNB; n++){
      float w = nm[b*NNB + n];
      float4 v = *(const float4*)(xnb + (size_t)(b*NNB + n)*DIM + d);
      acc.x += w*v.x; acc.y += w*v.y; acc.z += w*v.z; acc.w += w*v.w;
      wsum += w;
    }
    float inv = 1.f/wsum;
    acc.x*=inv; acc.y*=inv; acc.z*=inv; acc.w*=inv;
    *(float4*)(xnl + d) = acc;
  }
  __syncthreads();
  {  // q partial: lane ln -> row h*64+ln of qw, wave wv -> 256-d chunk
    const float* qrow = qw + (size_t)(h*HD + ln)*DIM + wv*256;
    const float* xrow = xnl + wv*256;
    float part = 0.f;
    #pragma unroll 16
    for (int i=0; i<64; i++){
      float4 a = *(const float4*)(qrow + i*4);
      float4 c = *(const float4*)(xrow + i*4);
      part += a.x*c.x + a.y*c.y + a.z*c.z + a.w*c.w;
    }
    qp[wv*64 + ln] = part;
  }
  __syncthreads();
  if (wv == 0){
    float qv = qp[ln] + qp[64+ln] + qp[128+ln] + qp[192+ln];
    ql[ln] = (qv + qb[h*HD + ln]) * 0.125f;
  }
  __syncthreads();
  {  // p[b,h,d] = sum_j ql[j]*kw[h*64+j,d]
    int d = tid*4;
    float4 acc = {0,0,0,0};
    #pragma unroll 8
    for (int j=0; j<HD; j++){
      float qj = ql[j];
      float4 kv = *(const float4*)(kw + (size_t)(h*HD + j)*DIM + d);
      acc.x += qj*kv.x; acc.y += qj*kv.y; acc.z += qj*kv.z; acc.w += qj*kv.w;
    }
    *(float4*)(p + (size_t)(b*NH + h)*DIM + d) = acc;
  }
}

// ---------------- K2: scp[kc][b,h,s] = x[b,s,kc-chunk].p[b,h,kc-chunk] -------
// grid (32 sc, 8 b, 4 kc) = 1024 blocks (4/CU). Tile 32 s x 16 h; lane covers
// (s = ln&31, d-half = ln>>5), halves merged by shfl_xor(32).
__global__ void k_scores(const float* __restrict__ x, const float* __restrict__ p,
                         float* __restrict__ scp){
  int s0 = blockIdx.x * 32;
  int b  = blockIdx.y;
  int kc = blockIdx.z;
  int kbase = kc * 256;
  int tid = threadIdx.x;
  __shared__ float4 plds[256*5];      // [d][h/4] transposed p chunk (20 KB)
  __shared__ float  xlds[32*68];      // [s][d] 32x64 tile, pad 68 (8.7 KB)
  float* pf = (float*)plds;
  #pragma unroll
  for (int it=0; it<16; it++){        // stage p chunk: 256 d x 16 h
    int idx = it*256 + tid;
    int d = idx & 255, h = idx >> 8;
    pf[d*20 + h] = p[(size_t)(b*NH + h)*DIM + kbase + d];
  }
  int ln = tid & 63, g = tid >> 6;    // wave-uniform head-quad g
  int s = ln & 31, half = ln >> 5;    // d-half split within wave
  float acc[4] = {0.f,0.f,0.f,0.f};
  for (int dk=0; dk<4; dk++){
    __syncthreads();
    #pragma unroll
    for (int it=0; it<2; it++){       // stage x tile 32 s x 64 d via float4
      int idx = it*256 + tid;
      int dd4 = idx & 15, ss = idx >> 4;
      float4 v = *(const float4*)(x + (size_t)(b*SEQ + s0 + ss)*DIM + kbase + dk*64 + dd4*4);
      *(float4*)(xlds + ss*68 + dd4*4) = v;
    }
    __syncthreads();
    #pragma unroll
    for (int j=0; j<8; j++){
      int dd4 = half*8 + j;
      float4 xq = *(const float4*)(xlds + s*68 + dd4*4);
      int dbase = (dk*64 + dd4*4)*5 + g;
      float4 p0 = plds[dbase], p1 = plds[dbase+5], p2 = plds[dbase+10], p3 = plds[dbase+15];
      acc[0] += xq.x*p0.x + xq.y*p1.x + xq.z*p2.x + xq.w*p3.x;
      acc[1] += xq.x*p0.y + xq.y*p1.y + xq.z*p2.y + xq.w*p3.y;
      acc[2] += xq.x*p0.z + xq.y*p1.z + xq.z*p2.z + xq.w*p3.z;
      acc[3] += xq.x*p0.w + xq.y*p1.w + xq.z*p2.w + xq.w*p3.w;
    }
  }
  #pragma unroll
  for (int u=0; u<4; u++) acc[u] += __shfl_xor(acc[u], 32, 64);  // merge d-halves
  if (half == 0){
    float* slab = scp + (size_t)kc*(BS*NH*SEQ);
    #pragma unroll
    for (int u=0; u<4; u++)
      slab[(size_t)(b*NH + g*4 + u)*SEQ + s0 + s] = acc[u];
  }
}

// ---------------- K3: fused exp + weighted pool (softmax-free) --------------
// e[s,h] = mask * exp(sum_kc scp); num partial = sum_s e*x; den partial.
// grid (4 dc, 8 b, 32 scn) = 1024 blocks; wave wv -> heads wv*4..+3; s-chunk 32.
__global__ void k_wpe(const float* __restrict__ x, const float* __restrict__ scp,
                      const int* __restrict__ mask,
                      float* __restrict__ nump, float* __restrict__ denp){
  int dc = blockIdx.x, b = blockIdx.y, scn = blockIdx.z;
  int tid = threadIdx.x;
  __shared__ float4 wlds[32*5];       // [s][h/4] e-values (2.5 KB)
  float* wf = (float*)wlds;
  #pragma unroll
  for (int it=0; it<2; it++){         // compute e for 32 s x 16 h
    int idx = it*256 + tid;
    int ss = idx >> 4, hh = idx & 15;
    int s  = scn*32 + ss;
    float sc = 0.f;
    #pragma unroll
    for (int kc=0; kc<4; kc++)
      sc += scp[(size_t)kc*(BS*NH*SEQ) + (size_t)(b*NH + hh)*SEQ + s];
    wf[ss*20 + hh] = mask[b*SEQ + s] ? __expf(sc) : 0.f;
  }
  __syncthreads();
  if (dc == 0 && tid < 16){           // den partial per head (once per (b,scn))
    float dsum = 0.f;
    #pragma unroll 16
    for (int ss=0; ss<32; ss++) dsum += wf[ss*20 + tid];
    denp[(scn*BS + b)*NH + tid] = dsum;
  }
  int ln = tid & 63, wv = tid >> 6;
  int d = dc*256 + ln*4;
  const float* xbase = x + (size_t)(b*SEQ + scn*32)*DIM + d;
  float4 a0={0,0,0,0}, a1={0,0,0,0}, a2={0,0,0,0}, a3={0,0,0,0};
  for (int sb=0; sb<32; sb+=8){
    float4 xq[8];
    #pragma unroll
    for (int u=0; u<8; u++)
      xq[u] = *(const float4*)(xbase + (size_t)(sb+u)*DIM);   // 8 loads in flight
    #pragma unroll
    for (int u=0; u<8; u++){
      float4 wq = wlds[(sb+u)*5 + wv];  // wave-uniform broadcast
      a0.x+=xq[u].x*wq.x; a0.y+=xq[u].y*wq.x; a0.z+=xq[u].z*wq.x; a0.w+=xq[u].w*wq.x;
      a1.x+=xq[u].x*wq.y; a1.y+=xq[u].y*wq.y; a1.z+=xq[u].z*wq.y; a1.w+=xq[u].w*wq.y;
      a2.x+=xq[u].x*wq.z; a2.y+=xq[u].y*wq.z; a2.z+=xq[u].z*wq.z; a2.w+=xq[u].w*wq.z;
      a3.x+=xq[u].x*wq.w; a3.y+=xq[u].y*wq.w; a3.z+=xq[u].z*wq.w; a3.w+=xq[u].w*wq.w;
    }
  }
  float* dst = nump + (size_t)scn*(BS*NH*DIM) + (size_t)(b*NH + wv*4)*DIM + d;
  *(float4*)(dst                 ) = a0;
  *(float4*)(dst +   (size_t)DIM ) = a1;
  *(float4*)(dst + 2*(size_t)DIM ) = a2;
  *(float4*)(dst + 3*(size_t)DIM ) = a3;
}

// ---------------- K4: xw[b,h,d] = sum_scn num / sum_scn den ----------------
__global__ void k_xwred(const float* __restrict__ nump, const float* __restrict__ denp,
                        float* __restrict__ xw){
  int id = blockIdx.x*256 + threadIdx.x;   // 512 blocks -> 131072 ids
  int bh = id >> 10;                        // b*NH + h
  int b = bh >> 4, h = bh & 15;
  float den = 0.f;
  #pragma unroll
  for (int scn=0; scn<32; scn++) den += denp[(scn*BS + b)*NH + h];
  float num = 0.f;
  #pragma unroll
  for (int scn=0; scn<32; scn++) num += nump[(size_t)scn*(BS*NH*DIM) + id];
  xw[id] = num / den;
}

// ---------------- K5: ctx[b,jo] = xw[b,h(jo),:].vw[jo,:] + vb[jo] ----------
__global__ void k_ctx(const float* __restrict__ xw, const float* __restrict__ vw,
                      const float* __restrict__ vb, float* __restrict__ ctx){
  int wv = threadIdx.x >> 6, ln = threadIdx.x & 63;
  int jo = blockIdx.x*4 + wv;
  int h  = jo >> 6;
  float acc[BS] = {0,0,0,0,0,0,0,0};
  #pragma unroll
  for (int i=0; i<4; i++){
    int d = ln*4 + 256*i;
    float4 vv = *(const float4*)(vw + (size_t)jo*DIM + d);
    #pragma unroll
    for (int b=0; b<BS; b++){
      float4 xv = *(const float4*)(xw + (size_t)(b*NH + h)*DIM + d);
      acc[b] += vv.x*xv.x + vv.y*xv.y + vv.z*xv.z + vv.w*xv.w;
    }
  }
  #pragma unroll
  for (int off=32; off>=1; off>>=1){
    #pragma unroll
    for (int b=0; b<BS; b++) acc[b] += __shfl_down(acc[b], off, 64);
  }
  if (ln == 0){
    float bias = vb[jo];
    #pragma unroll
    for (int b=0; b<BS; b++) ctx[b*DIM + jo] = acc[b] + bias;
  }
}

// ---------------- K6: out_row[b,i] = ctx[b,:].ow[i,:] + ob[i] ----------------
__global__ void k_outrow(const float* __restrict__ ctx, const float* __restrict__ ow,
                         const float* __restrict__ ob, float* __restrict__ outr){
  int wv = threadIdx.x >> 6, ln = threadIdx.x & 63;
  int io = blockIdx.x*4 + wv;
  float acc[BS] = {0,0,0,0,0,0,0,0};
  #pragma unroll
  for (int i=0; i<4; i++){
    int d = ln*4 + 256*i;
    float4 wt = *(const float4*)(ow + (size_t)io*DIM + d);
    #pragma unroll
    for (int b=0; b<BS; b++){
      float4 cv = *(const float4*)(ctx + b*DIM + d);
      acc[b] += wt.x*cv.x + wt.y*cv.y + wt.z*cv.z + wt.w*cv.w;
    }
  }
  #pragma unroll
  for (int off=32; off>=1; off>>=1){
    #pragma unroll
    for (int b=0; b<BS; b++) acc[b] += __shfl_down(acc[b], off, 64);
  }
  if (ln == 0){
    float bias = ob[io];
    #pragma unroll
    for (int b=0; b<BS; b++) outr[b*DIM + io] = acc[b] + bias;
  }
}

// ---------------- K7: out[b,s,:] = LN(out_row[b]+x[b,s,:])*g + beta ---------
__global__ void k_ln(const float* __restrict__ x, const float* __restrict__ outr,
                     const float* __restrict__ g, const float* __restrict__ bt,
                     float* __restrict__ out){
  int row = blockIdx.x;
  int b = row >> 10;
  size_t base = (size_t)row * DIM;
  int tid = threadIdx.x;
  float4 xv = ((const float4*)(x + base))[tid];
  float4 ov = ((const float4*)(outr + (size_t)b*DIM))[tid];
  float4 h;
  h.x = xv.x + ov.x; h.y = xv.y + ov.y; h.z = xv.z + ov.z; h.w = xv.w + ov.w;
  float s  = h.x + h.y + h.z + h.w;
  float s2 = h.x*h.x + h.y*h.y + h.z*h.z + h.w*h.w;
  #pragma unroll
  for (int off=32; off>=1; off>>=1){
    s  += __shfl_xor(s,  off, 64);
    s2 += __shfl_xor(s2, off, 64);
  }
  __shared__ float r1[4], r2[4];
  int wv = tid >> 6, ln = tid & 63;
  if (ln == 0){ r1[wv] = s; r2[wv] = s2; }
  __syncthreads();
  s  = r1[0] + r1[1] + r1[2] + r1[3];
  s2 = r2[0] + r2[1] + r2[2] + r2[3];
  float mu   = s  * (1.f/1024.f);
  float var  = s2 * (1.f/1024.f) - mu*mu;
  float rstd = rsqrtf(var + 1e-12f);
  float4 gv = ((const float4*)g)[tid];
  float4 bv = ((const float4*)bt)[tid];
  float4 y;
  y.x = (h.x - mu)*rstd*gv.x + bv.x;
  y.y = (h.y - mu)*rstd*gv.y + bv.y;
  y.z = (h.z - mu)*rstd*gv.z + bv.z;
  y.w = (h.w - mu)*rstd*gv.w + bv.w;
  ((float4*)(out + base))[tid] = y;
}

extern "C" void kernel_launch(void* const* d_in, const int* in_sizes, int n_in,
                              void* d_out, int out_size, void* d_ws, size_t ws_size,
                              hipStream_t stream) {
  const float* x    = (const float*)d_in[0];
  const float* xnb  = (const float*)d_in[1];
  const int*   mask = (const int*  )d_in[2];
  const float* nm   = (const float*)d_in[3];
  const float* qw   = (const float*)d_in[4];
  const float* qb   = (const float*)d_in[5];
  const float* kw   = (const float*)d_in[6];
  // d_in[7] = kb: softmax-invariant constant, unused
  const float* vw   = (const float*)d_in[8];
  const float* vb   = (const float*)d_in[9];
  const float* ow   = (const float*)d_in[10];
  const float* ob   = (const float*)d_in[11];
  const float* lng  = (const float*)d_in[12];
  const float* lnb  = (const float*)d_in[13];
  float* out = (float*)d_out;

  float* ws   = (float*)d_ws;              // ~20 MB of ~256 MB ws
  float* p    = ws + OF_P;
  float* scp  = ws + OF_SCP;               // 4 kc-slabs
  float* nump = ws + OF_NUMP;              // 32 s-chunk slabs
  float* denp = ws + OF_DENP;              // 32 x 128
  float* xw   = ws + OF_XW;
  float* ctx  = ws + OF_CTX;
  float* outr = ws + OF_OUTR;

  k_prep  <<<128,             256, 0, stream>>>(xnb, nm, qw, qb, kw, p);
  k_scores<<<dim3(32,BS,4),   256, 0, stream>>>(x, p, scp);
  k_wpe   <<<dim3(4,BS,32),   256, 0, stream>>>(x, scp, mask, nump, denp);
  k_xwred <<<512,             256, 0, stream>>>(nump, denp, xw);
  k_ctx   <<<256,             256, 0, stream>>>(xw, vw, vb, ctx);
  k_outrow<<<256,             256, 0, stream>>>(ctx, ow, ob, outr);
  k_ln    <<<BS*SEQ,          256, 0, stream>>>(x, outr, lng, lnb, out);
}

// Round 11
// 170.527 us; speedup vs baseline: 1.4533x; 1.4533x over previous
//
#include <hip/hip_runtime.h>
#include <hip/hip_bf16.h>

// NeighborAttention on MI355X. fp32 in/out, int32 mask.
// KEY INSIGHT (R0): query = broadcast of masked neighbor-mean -> all seq
// positions share one query per (b,h). Attention collapses to GEMV-scale work.
// Recorded: SW device barriers ~40us each (R6/R7 dead end); graph launches
// ~1us (R8); harness carries ~41us ws-poison fill + ~10us restore (fixed);
// R9's 1024-block k_scores thrashed L2 (280MB observed vs 52MB logical) ->
// reverted. R5 proved fused scores->exp->pool math at absmax parity but died
// at 4 waves/CU.
// R10: fused k_att2 = R5 dataflow at 16 waves/CU: 1024-thread blocks, grid
// (32 sc x 8 b) = 256 blocks = 1 block/CU. Phase 1: R5's verified accA/accB
// inner loop, waves = (head-quad x dk-quarter), one x-stage per kc, spart
// cross-wave merge aliasing plds (sync-separated). Phase 2: R8's k_wpe body
// (8-deep float4 global loads, L2-hot). LDS 53.8KB. 6 launches.

#define DIM  1024
#define NH   16
#define HD   64
#define BS   8
#define SEQ  1024
#define NNB  50

// workspace offsets (floats), all 16B-aligned
#define OF_P     16
#define OF_NUMP  131088       // 32 slabs x 131072
#define OF_DENP  4325392
#define OF_XW    4329488
#define OF_CTX   4460560
#define OF_OUTR  4468752      // ~17.9 MB of ~256 MB ws

// ---------------- K1: fused neighbor-pool + q + p, one block per (h,b) -------
__global__ void k_prep(const float* __restrict__ xnb, const float* __restrict__ nm,
                       const float* __restrict__ qw, const float* __restrict__ qb,
                       const float* __restrict__ kw, float* __restrict__ p){
  int h = blockIdx.x & 15, b = blockIdx.x >> 4;
  int tid = threadIdx.x, wv = tid >> 6, ln = tid & 63;
  __shared__ float xnl[1024];
  __shared__ float qp[256];
  __shared__ float ql[64];
  {  // masked neighbor mean
    int d = tid*4;
    float4 acc = {0,0,0,0}; float wsum = 0.f;
    #pragma unroll 10
    for (int n=0; n<NNB; n++){
      float w = nm[b*NNB + n];
      float4 v = *(const float4*)(xnb + (size_t)(b*NNB + n)*DIM + d);
      acc.x += w*v.x; acc.y += w*v.y; acc.z += w*v.z; acc.w += w*v.w;
      wsum += w;
    }
    float inv = 1.f/wsum;
    acc.x*=inv; acc.y*=inv; acc.z*=inv; acc.w*=inv;
    *(float4*)(xnl + d) = acc;
  }
  __syncthreads();
  {  // q partial: lane ln -> row h*64+ln of qw, wave wv -> 256-d chunk
    const float* qrow = qw + (size_t)(h*HD + ln)*DIM + wv*256;
    const float* xrow = xnl + wv*256;
    float part = 0.f;
    #pragma unroll 16
    for (int i=0; i<64; i++){
      float4 a = *(const float4*)(qrow + i*4);
      float4 c = *(const float4*)(xrow + i*4);
      part += a.x*c.x + a.y*c.y + a.z*c.z + a.w*c.w;
    }
    qp[wv*64 + ln] = part;
  }
  __syncthreads();
  if (wv == 0){
    float qv = qp[ln] + qp[64+ln] + qp[128+ln] + qp[192+ln];
    ql[ln] = (qv + qb[h*HD + ln]) * 0.125f;
  }
  __syncthreads();
  {  // p[b,h,d] = sum_j ql[j]*kw[h*64+j,d]
    int d = tid*4;
    float4 acc = {0,0,0,0};
    #pragma unroll 8
    for (int j=0; j<HD; j++){
      float qj = ql[j];
      float4 kv = *(const float4*)(kw + (size_t)(h*HD + j)*DIM + d);
      acc.x += qj*kv.x; acc.y += qj*kv.y; acc.z += qj*kv.z; acc.w += qj*kv.w;
    }
    *(float4*)(p + (size_t)(b*NH + h)*DIM + d) = acc;
  }
}

// ---------------- K2: fused scores + exp + weighted pool ---------------------
// grid (32 sc, 8 b), block 1024 = 16 waves. Wave w: head-quad g=w&3,
// dk-quarter dkq=w>>2. Lane: sA=ln&15 (covers sA and sA+16), qr=ln>>4.
// Phase 1: full-K scores accumulated in regs over kc; merge qr by shfl,
// dkq via spart (aliases plds, sync-separated); exp (no max-sub, proven
// R5/R8), mask -> elds; den by tid<16. Phase 2: num[h,d] += e*x with x
// streamed from global (L2-hot), 8-deep float4 ILP; plain slab stores.
__global__ void __launch_bounds__(1024, 1)
k_att2(const float* __restrict__ x, const float* __restrict__ p,
       const int* __restrict__ mask,
       float* __restrict__ nump, float* __restrict__ denp){
  int sc = blockIdx.x;
  int b  = blockIdx.y;
  int s0 = sc * 32;
  int tid = threadIdx.x;
  int w = tid >> 6, ln = tid & 63;
  int g = w & 3, dkq = w >> 2;        // wave-uniform
  int sA = ln & 15, qr = ln >> 4;

  __shared__ __align__(16) unsigned char smem[53760];
  float4* xlds4 = (float4*)smem;                   // [32 s][65 f4] = 33280 B
  float4* plds4 = (float4*)(smem + 33280);         // [256 d][5 f4] = 20480 B
  float*  spart = (float*)(smem + 33280);          // aliases plds: 8192 B
  float*  ef    = (float*)(smem + 33280 + 8192);   // [32 s][20] = 2560 B
  float*  pf    = (float*)plds4;
  float*  xf    = (float*)xlds4;

  float accA[4] = {0,0,0,0}, accB[4] = {0,0,0,0};
  for (int kc=0; kc<4; kc++){
    int kbase = kc*256;
    __syncthreads();                  // prior compute done before restaging
    #pragma unroll
    for (int it=0; it<4; it++){       // stage p chunk: 256 d x 16 h
      int idx = it*1024 + tid;
      int d = idx & 255, h = idx >> 8;
      pf[d*20 + h] = p[(size_t)(b*NH + h)*DIM + kbase + d];
    }
    #pragma unroll
    for (int it=0; it<2; it++){       // stage x tile 32 s x 256 d (float4)
      int idx = it*1024 + tid;
      int dd4 = idx & 63, ss = idx >> 6;
      float4 v = *(const float4*)(x + (size_t)(b*SEQ + s0 + ss)*DIM + kbase + dd4*4);
      xlds4[ss*65 + dd4] = v;
    }
    __syncthreads();
    #pragma unroll
    for (int j=0; j<4; j++){          // this wave's dk-quarter, lane's d-quarter
      int dd4 = dkq*16 + qr*4 + j;
      float4 xa = xlds4[sA*65 + dd4];
      float4 xb = xlds4[(sA+16)*65 + dd4];
      int dbase = dd4*20 + g;         // (dd4*4)*5 + g
      float4 p0 = plds4[dbase], p1 = plds4[dbase+5], p2 = plds4[dbase+10], p3 = plds4[dbase+15];
      accA[0] += xa.x*p0.x + xa.y*p1.x + xa.z*p2.x + xa.w*p3.x;
      accA[1] += xa.x*p0.y + xa.y*p1.y + xa.z*p2.y + xa.w*p3.y;
      accA[2] += xa.x*p0.z + xa.y*p1.z + xa.z*p2.z + xa.w*p3.z;
      accA[3] += xa.x*p0.w + xa.y*p1.w + xa.z*p2.w + xa.w*p3.w;
      accB[0] += xb.x*p0.x + xb.y*p1.x + xb.z*p2.x + xb.w*p3.x;
      accB[1] += xb.x*p0.y + xb.y*p1.y + xb.z*p2.y + xb.w*p3.y;
      accB[2] += xb.x*p0.z + xb.y*p1.z + xb.z*p2.z + xb.w*p3.z;
      accB[3] += xb.x*p0.w + xb.y*p1.w + xb.z*p2.w + xb.w*p3.w;
    }
  }
  // merge the lane-level d-quarters (qr): xor over lane bits 4,5
  #pragma unroll
  for (int u=0; u<4; u++){
    accA[u] += __shfl_xor(accA[u], 16, 64);
    accA[u] += __shfl_xor(accA[u], 32, 64);
    accB[u] += __shfl_xor(accB[u], 16, 64);
    accB[u] += __shfl_xor(accB[u], 32, 64);
  }
  __syncthreads();                    // all waves done reading plds (alias!)
  if (qr == 0){                       // lanes 0..15: write dkq partials
    #pragma unroll
    for (int u=0; u<4; u++){
      spart[((dkq*4 + g)*32 + sA)*4 + u]      = accA[u];
      spart[((dkq*4 + g)*32 + sA + 16)*4 + u] = accB[u];
    }
  }
  __syncthreads();
  if (tid < 512){                     // sum dkq partials, exp, mask -> elds
    int u = tid & 3, s = (tid >> 2) & 31, hq = tid >> 7;
    float v = 0.f;
    #pragma unroll
    for (int dq=0; dq<4; dq++) v += spart[((dq*4 + hq)*32 + s)*4 + u];
    ef[s*20 + hq*4 + u] = mask[b*SEQ + s0 + s] ? __expf(v) : 0.f;
  }
  __syncthreads();
  if (tid < 16){                      // den partial per head
    float dsum = 0.f;
    #pragma unroll 16
    for (int s=0; s<32; s++) dsum += ef[s*20 + tid];
    denp[(sc*BS + b)*NH + tid] = dsum;
  }
  // Phase 2: wave w -> head-quad g, d-quarter dkq of full DIM; lane -> 4 d.
  {
    int d = dkq*256 + ln*4;
    const float* xbase = x + (size_t)(b*SEQ + s0)*DIM + d;
    float4* ef4 = (float4*)ef;
    float4 a0={0,0,0,0}, a1={0,0,0,0}, a2={0,0,0,0}, a3={0,0,0,0};
    for (int sb=0; sb<32; sb+=8){
      float4 xq[8];
      #pragma unroll
      for (int u=0; u<8; u++)
        xq[u] = *(const float4*)(xbase + (size_t)(sb+u)*DIM);  // 8 loads in flight
      #pragma unroll
      for (int u=0; u<8; u++){
        float4 e4 = ef4[(sb+u)*5 + g];   // wave-uniform broadcast
        a0.x+=xq[u].x*e4.x; a0.y+=xq[u].y*e4.x; a0.z+=xq[u].z*e4.x; a0.w+=xq[u].w*e4.x;
        a1.x+=xq[u].x*e4.y; a1.y+=xq[u].y*e4.y; a1.z+=xq[u].z*e4.y; a1.w+=xq[u].w*e4.y;
        a2.x+=xq[u].x*e4.z; a2.y+=xq[u].y*e4.z; a2.z+=xq[u].z*e4.z; a2.w+=xq[u].w*e4.z;
        a3.x+=xq[u].x*e4.w; a3.y+=xq[u].y*e4.w; a3.z+=xq[u].z*e4.w; a3.w+=xq[u].w*e4.w;
      }
    }
    float* dst = nump + (size_t)sc*(BS*NH*DIM) + (size_t)(b*NH + g*4)*DIM + d;
    *(float4*)(dst                 ) = a0;
    *(float4*)(dst +   (size_t)DIM ) = a1;
    *(float4*)(dst + 2*(size_t)DIM ) = a2;
    *(float4*)(dst + 3*(size_t)DIM ) = a3;
  }
}

// ---------------- K3: xw[b,h,d] = sum_sc num / sum_sc den ----------------
__global__ void k_xwred(const float* __restrict__ nump, const float* __restrict__ denp,
                        float* __restrict__ xw){
  int id = blockIdx.x*256 + threadIdx.x;   // 512 blocks -> 131072 ids
  int bh = id >> 10;                        // b*NH + h
  int b = bh >> 4, h = bh & 15;
  float den = 0.f;
  #pragma unroll
  for (int scn=0; scn<32; scn++) den += denp[(scn*BS + b)*NH + h];
  float num = 0.f;
  #pragma unroll
  for (int scn=0; scn<32; scn++) num += nump[(size_t)scn*(BS*NH*DIM) + id];
  xw[id] = num / den;
}

// ---------------- K4: ctx[b,jo] = xw[b,h(jo),:].vw[jo,:] + vb[jo] ----------
__global__ void k_ctx(const float* __restrict__ xw, const float* __restrict__ vw,
                      const float* __restrict__ vb, float* __restrict__ ctx){
  int wv = threadIdx.x >> 6, ln = threadIdx.x & 63;
  int jo = blockIdx.x*4 + wv;
  int h  = jo >> 6;
  float acc[BS] = {0,0,0,0,0,0,0,0};
  #pragma unroll
  for (int i=0; i<4; i++){
    int d = ln*4 + 256*i;
    float4 vv = *(const float4*)(vw + (size_t)jo*DIM + d);
    #pragma unroll
    for (int b=0; b<BS; b++){
      float4 xv = *(const float4*)(xw + (size_t)(b*NH + h)*DIM + d);
      acc[b] += vv.x*xv.x + vv.y*xv.y + vv.z*xv.z + vv.w*xv.w;
    }
  }
  #pragma unroll
  for (int off=32; off>=1; off>>=1){
    #pragma unroll
    for (int b=0; b<BS; b++) acc[b] += __shfl_down(acc[b], off, 64);
  }
  if (ln == 0){
    float bias = vb[jo];
    #pragma unroll
    for (int b=0; b<BS; b++) ctx[b*DIM + jo] = acc[b] + bias;
  }
}

// ---------------- K5: out_row[b,i] = ctx[b,:].ow[i,:] + ob[i] ----------------
__global__ void k_outrow(const float* __restrict__ ctx, const float* __restrict__ ow,
                         const float* __restrict__ ob, float* __restrict__ outr){
  int wv = threadIdx.x >> 6, ln = threadIdx.x & 63;
  int io = blockIdx.x*4 + wv;
  float acc[BS] = {0,0,0,0,0,0,0,0};
  #pragma unroll
  for (int i=0; i<4; i++){
    int d = ln*4 + 256*i;
    float4 wt = *(const float4*)(ow + (size_t)io*DIM + d);
    #pragma unroll
    for (int b=0; b<BS; b++){
      float4 cv = *(const float4*)(ctx + b*DIM + d);
      acc[b] += wt.x*cv.x + wt.y*cv.y + wt.z*cv.z + wt.w*cv.w;
    }
  }
  #pragma unroll
  for (int off=32; off>=1; off>>=1){
    #pragma unroll
    for (int b=0; b<BS; b++) acc[b] += __shfl_down(acc[b], off, 64);
  }
  if (ln == 0){
    float bias = ob[io];
    #pragma unroll
    for (int b=0; b<BS; b++) outr[b*DIM + io] = acc[b] + bias;
  }
}

// ---------------- K6: out[b,s,:] = LN(out_row[b]+x[b,s,:])*g + beta ---------
__global__ void k_ln(const float* __restrict__ x, const float* __restrict__ outr,
                     const float* __restrict__ g, const float* __restrict__ bt,
                     float* __restrict__ out){
  int row = blockIdx.x;
  int b = row >> 10;
  size_t base = (size_t)row * DIM;
  int tid = threadIdx.x;
  float4 xv = ((const float4*)(x + base))[tid];
  float4 ov = ((const float4*)(outr + (size_t)b*DIM))[tid];
  float4 h;
  h.x = xv.x + ov.x; h.y = xv.y + ov.y; h.z = xv.z + ov.z; h.w = xv.w + ov.w;
  float s  = h.x + h.y + h.z + h.w;
  float s2 = h.x*h.x + h.y*h.y + h.z*h.z + h.w*h.w;
  #pragma unroll
  for (int off=32; off>=1; off>>=1){
    s  += __shfl_xor(s,  off, 64);
    s2 += __shfl_xor(s2, off, 64);
  }
  __shared__ float r1[4], r2[4];
  int wv = tid >> 6, ln = tid & 63;
  if (ln == 0){ r1[wv] = s; r2[wv] = s2; }
  __syncthreads();
  s  = r1[0] + r1[1] + r1[2] + r1[3];
  s2 = r2[0] + r2[1] + r2[2] + r2[3];
  float mu   = s  * (1.f/1024.f);
  float var  = s2 * (1.f/1024.f) - mu*mu;
  float rstd = rsqrtf(var + 1e-12f);
  float4 gv = ((const float4*)g)[tid];
  float4 bv = ((const float4*)bt)[tid];
  float4 y;
  y.x = (h.x - mu)*rstd*gv.x + bv.x;
  y.y = (h.y - mu)*rstd*gv.y + bv.y;
  y.z = (h.z - mu)*rstd*gv.z + bv.z;
  y.w = (h.w - mu)*rstd*gv.w + bv.w;
  ((float4*)(out + base))[tid] = y;
}

extern "C" void kernel_launch(void* const* d_in, const int* in_sizes, int n_in,
                              void* d_out, int out_size, void* d_ws, size_t ws_size,
                              hipStream_t stream) {
  const float* x    = (const float*)d_in[0];
  const float* xnb  = (const float*)d_in[1];
  const int*   mask = (const int*  )d_in[2];
  const float* nm   = (const float*)d_in[3];
  const float* qw   = (const float*)d_in[4];
  const float* qb   = (const float*)d_in[5];
  const float* kw   = (const float*)d_in[6];
  // d_in[7] = kb: softmax-invariant constant, unused
  const float* vw   = (const float*)d_in[8];
  const float* vb   = (const float*)d_in[9];
  const float* ow   = (const float*)d_in[10];
  const float* ob   = (const float*)d_in[11];
  const float* lng  = (const float*)d_in[12];
  const float* lnb  = (const float*)d_in[13];
  float* out = (float*)d_out;

  float* ws   = (float*)d_ws;              // ~17.9 MB of ~256 MB ws
  float* p    = ws + OF_P;
  float* nump = ws + OF_NUMP;              // 32 s-chunk slabs
  float* denp = ws + OF_DENP;
  float* xw   = ws + OF_XW;
  float* ctx  = ws + OF_CTX;
  float* outr = ws + OF_OUTR;

  k_prep  <<<128,           256,  0, stream>>>(xnb, nm, qw, qb, kw, p);
  k_att2  <<<dim3(32,BS),   1024, 0, stream>>>(x, p, mask, nump, denp);
  k_xwred <<<512,           256,  0, stream>>>(nump, denp, xw);
  k_ctx   <<<256,           256,  0, stream>>>(xw, vw, vb, ctx);
  k_outrow<<<256,           256,  0, stream>>>(ctx, ow, ob, outr);
  k_ln    <<<BS*SEQ,        256,  0, stream>>>(x, outr, lng, lnb, out);
}